// Round 6
// baseline (1206.959 us; speedup 1.0000x reference)
//
#include <hip/hip_runtime.h>
#include <math.h>

#define SQ2G 4.42718872424f   // sqrtf(19.6f)

__device__ __forceinline__ float wave_sum(float v) {
#pragma unroll
    for (int o = 32; o > 0; o >>= 1) v += __shfl_xor(v, o);
    return v;
}

// One cooperative kernel, whole 16-layer cascade. 256 blocks x 256 threads,
// 1 block/CU, 4 buckets/block (one wave each). Layer barrier = distributed
// per-block stage flags (no grid.sync, no same-line RMW storm).
// flags[blk] (int) = number of mid layers block blk has published; headflag =
// head-bucket row published. 0xAA ws poison = negative int => no init needed.
__global__ __launch_bounds__(256, 1)
void cascade_kernel(const float* __restrict__ H0p, const float* __restrict__ Hmid,
                    const float* __restrict__ Hlast, const float* __restrict__ S0,
                    const float* __restrict__ Smid, const float* __restrict__ Slast,
                    const float* __restrict__ th0, const float* __restrict__ thmid,
                    const float* __restrict__ thlast, const float* __restrict__ precip,
                    float* __restrict__ out, int* __restrict__ headflag,
                    int* __restrict__ flags, float* __restrict__ PA, float* __restrict__ PB)
{
    __shared__ float acc[1024];
    const int tid  = threadIdx.x;
    const int lane = tid & 63;
    const int w    = tid >> 6;
    const int blk  = blockIdx.x;
    const int b    = blk * 4 + w;

    const float pl = precip[0] * 0.0625f;        // precip / 16 (exact)
    const float pb = pl * (1.0f / 1024.0f);      // per-bucket share (exact)

    // prefetch mid-layer-0 S/theta rows for this wave's bucket (all blocks)
    float2 sv[16]; float tv[16];
    {
        const float2* S2 = (const float2*)Smid + (size_t)b * 1024;
        const float*  th = thmid + (size_t)b * 1024;
#pragma unroll
        for (int c = 0; c < 16; ++c) { sv[c] = S2[c * 64 + lane]; tv[c] = th[c * 64 + lane]; }
    }

    // ---- head bucket: block 0, wave 0 ----
    if (blk == 0 && w == 0) {
        const float H = H0p[0];
        const float2* S2 = (const float2*)S0;
        float e0a[16], c0a[16];
#pragma unroll
        for (int c = 0; c < 16; ++c) {
            float2 s = S2[c * 64 + lane];
            float  t = th0[c * 64 + lane];
            e0a[c] = H - s.x;
            c0a[c] = t * s.y * SQ2G;
        }
        float e00 = __shfl(e0a[0], 0), c00 = __shfl(c0a[0], 0);
        float d0  = e00 + pl;
        float q0  = (d0 > 0.0f) ? c00 * sqrtf(d0) : 0.0f;
        float cum = q0;
#pragma unroll
        for (int c = 0; c < 16; ++c) {
            unsigned long long avail = (c == 0) ? ~1ull : ~0ull;
            float qm = 0.0f;
            for (;;) {
                unsigned long long cand = __ballot(e0a[c] > 0.5f * cum) & avail;
                if (!cand) break;
                int j = __builtin_ctzll(cand);
                avail = (j >= 63) ? 0ull : (~0ull << (j + 1));
                float ej = __shfl(e0a[c], j);
                float cj = __shfl(c0a[c], j);
                float q  = cj * sqrtf(fmaf(-0.5f, cum, ej));   // d > 0 by ballot
                cum += q;
                if (lane == j) qm = q;
                if (!avail) break;
            }
            int i = c * 64 + lane;
            PA[i] = (i == 0) ? q0 : qm;
        }
        if (lane == 0) out[0] = (H - cum) + pl;   // H0_new
        __threadfence();                           // release PA row + out
        if (lane == 0)
            __hip_atomic_store(headflag, 1, __ATOMIC_RELEASE, __HIP_MEMORY_SCOPE_AGENT);
    }

    float* cur = PA;
    float* nxt = PB;

    for (int l = 0; l < 14; ++l) {
        // transform current layer rows (consumes sv/tv loads)
        const float H = Hmid[l * 1024 + b];
        float e[16], cc[16];
#pragma unroll
        for (int c = 0; c < 16; ++c) { e[c] = H - sv[c].x; cc[c] = tv[c] * sv[c].y * SQ2G; }

        // issue next layer's prefetch (in flight across barrier + drain)
        if (l < 13) {
            const float2* S2 = (const float2*)Smid + ((size_t)(l + 1) * 1024 + b) * 1024;
            const float*  th = thmid + ((size_t)(l + 1) * 1024 + b) * 1024;
#pragma unroll
            for (int c = 0; c < 16; ++c) { sv[c] = S2[c * 64 + lane]; tv[c] = th[c * 64 + lane]; }
        }

#pragma unroll
        for (int r = 0; r < 4; ++r) acc[r * 256 + tid] = 0.0f;

        // ---- barrier: wait for stage-l partials ----
        if (w == 0) {
            if (l == 0) {
                if (lane == 0)
                    while (__hip_atomic_load(headflag, __ATOMIC_ACQUIRE,
                                             __HIP_MEMORY_SCOPE_AGENT) < 1)
                        __builtin_amdgcn_s_sleep(2);
            } else {
                for (;;) {
                    int m0 = __hip_atomic_load(&flags[lane],       __ATOMIC_ACQUIRE, __HIP_MEMORY_SCOPE_AGENT);
                    int m1 = __hip_atomic_load(&flags[lane + 64],  __ATOMIC_ACQUIRE, __HIP_MEMORY_SCOPE_AGENT);
                    int m2 = __hip_atomic_load(&flags[lane + 128], __ATOMIC_ACQUIRE, __HIP_MEMORY_SCOPE_AGENT);
                    int m3 = __hip_atomic_load(&flags[lane + 192], __ATOMIC_ACQUIRE, __HIP_MEMORY_SCOPE_AGENT);
                    int mn = min(min(m0, m1), min(m2, m3));
                    if (__all(mn >= l)) break;        // poison (0xAA..) is negative
                    __builtin_amdgcn_s_sleep(2);
                }
            }
        }
        __syncthreads();
        __threadfence();   // acquire side: partials visible to plain loads

        // ---- gather inflow ----
        float inflow;
        if (l == 0) {
            inflow = pb + cur[b];                 // single source row (head)
        } else {
            float part = 0.0f;
#pragma unroll
            for (int k = 0; k < 4; ++k)
                part += cur[(size_t)(k * 64 + lane) * 1024 + b];
            inflow = pb + wave_sum(part);
        }

        // ---- drain ----
        float e0 = __shfl(e[0], 0), c0 = __shfl(cc[0], 0);
        float d0 = e0 + inflow;                   // spigot 0 sees H + inflow
        float q0 = (d0 > 0.0f) ? c0 * sqrtf(d0) : 0.0f;
        float cum = q0;
        if (lane == 0 && q0 != 0.0f) atomicAdd(&acc[0], q0);

#pragma unroll
        for (int c = 0; c < 16; ++c) {
            unsigned long long avail = (c == 0) ? ~1ull : ~0ull;
            float qm = 0.0f;
            for (;;) {
                unsigned long long cand = __ballot(e[c] > 0.5f * cum) & avail;
                if (!cand) break;
                int j = __builtin_ctzll(cand);
                avail = (j >= 63) ? 0ull : (~0ull << (j + 1));
                float ej = __shfl(e[c], j);
                float cj = __shfl(cc[c], j);
                float q  = cj * sqrtf(fmaf(-0.5f, cum, ej));
                cum += q;
                if (lane == j) qm = q;
                if (!avail) break;
            }
            if (qm != 0.0f) atomicAdd(&acc[c * 64 + lane], qm);
        }
        if (lane == 0) out[1 + l * 1024 + b] = (H - cum) + inflow;   // H_mid_new

        // ---- publish partial row ----
        __syncthreads();
#pragma unroll
        for (int r = 0; r < 4; ++r)
            nxt[(size_t)blk * 1024 + r * 256 + tid] = acc[r * 256 + tid];
        __threadfence();   // every thread releases its own stores
        __syncthreads();   // all releases done before flag
        if (tid == 0)
            __hip_atomic_store(&flags[blk], l + 1, __ATOMIC_RELEASE, __HIP_MEMORY_SCOPE_AGENT);

        float* t = cur; cur = nxt; nxt = t;
    }

    // ---- last layer: wait stage 14, gather, 1 spigot per bucket ----
    if (w == 0) {
        for (;;) {
            int m0 = __hip_atomic_load(&flags[lane],       __ATOMIC_ACQUIRE, __HIP_MEMORY_SCOPE_AGENT);
            int m1 = __hip_atomic_load(&flags[lane + 64],  __ATOMIC_ACQUIRE, __HIP_MEMORY_SCOPE_AGENT);
            int m2 = __hip_atomic_load(&flags[lane + 128], __ATOMIC_ACQUIRE, __HIP_MEMORY_SCOPE_AGENT);
            int m3 = __hip_atomic_load(&flags[lane + 192], __ATOMIC_ACQUIRE, __HIP_MEMORY_SCOPE_AGENT);
            int mn = min(min(m0, m1), min(m2, m3));
            if (__all(mn >= 14)) break;
            __builtin_amdgcn_s_sleep(2);
        }
    }
    __syncthreads();
    __threadfence();

    {
        float part = 0.0f;
#pragma unroll
        for (int k = 0; k < 4; ++k)
            part += cur[(size_t)(k * 64 + lane) * 1024 + b];
        float inflow = pb + wave_sum(part);
        if (lane == 0) {
            float H  = Hlast[b];
            float2 s = ((const float2*)Slast)[b];
            float d  = (H + inflow) - s.x;
            float q  = (d > 0.0f) ? thlast[b] * sqrtf(19.6f * d) * s.y : 0.0f;
            out[1 + 14 * 1024 + b]        = (H - q) + inflow;   // H_last_new
            out[1 + 14 * 1024 + 1024 + b] = q;                  // q_last
        }
    }
}

extern "C" void kernel_launch(void* const* d_in, const int* in_sizes, int n_in,
                              void* d_out, int out_size, void* d_ws, size_t ws_size,
                              hipStream_t stream)
{
    (void)in_sizes; (void)n_in; (void)out_size; (void)ws_size;
    const float* H0     = (const float*)d_in[0];
    const float* Hmid   = (const float*)d_in[1];
    const float* Hlast  = (const float*)d_in[2];
    const float* S0     = (const float*)d_in[3];
    const float* Smid   = (const float*)d_in[4];
    const float* Slast  = (const float*)d_in[5];
    const float* th0    = (const float*)d_in[6];
    const float* thmid  = (const float*)d_in[7];
    const float* thlast = (const float*)d_in[8];
    const float* precip = (const float*)d_in[9];
    float* out = (float*)d_out;

    // ws layout: [headflag int][flags int*256] (poison 0xAA = negative ints,
    // spin tests are signed '>= stage' so no zero-init needed), then PA, PB.
    int*   headflag = (int*)d_ws;
    int*   flags    = headflag + 1;
    float* PA       = (float*)((char*)d_ws + 2048);
    float* PB       = PA + (size_t)256 * 1024;

    void* args[] = { (void*)&H0, (void*)&Hmid, (void*)&Hlast, (void*)&S0, (void*)&Smid,
                     (void*)&Slast, (void*)&th0, (void*)&thmid, (void*)&thlast,
                     (void*)&precip, (void*)&out, (void*)&headflag, (void*)&flags,
                     (void*)&PA, (void*)&PB };

    hipLaunchCooperativeKernel((const void*)cascade_kernel, dim3(256), dim3(256),
                               args, 0, stream);
}